// Round 6
// baseline (616.473 us; speedup 1.0000x reference)
//
#include <hip/hip_runtime.h>
#include <hip/hip_bf16.h>
#include <math.h>

#define BATCH 65536
#define DIM 256
#define KC 1024
#define COMMIT 0.25f
#define DECAY 0.99f
#define EPSV 1e-5f

// Output layout (floats, concatenated in reference return order)
#define O_ZQ   0                       // 65536*256
#define O_LOSS 16777216                // 1
#define O_PERP 16777217                // 1
#define O_IDX  16777218                // 65536 (indices written as float values)
#define O_EMB  16842754                // 1024*256 new_embedding
#define O_NCS  17104898                // 1024 new_ema_cluster_size
#define O_NEW  17105922                // 1024*256 new_ema_w

typedef __attribute__((ext_vector_type(8))) short bf16x8;
typedef __attribute__((ext_vector_type(4))) float f32x4;

typedef __attribute__((address_space(1))) const void* as1_cvp;
typedef __attribute__((address_space(3))) void* as3_vp;

__device__ __forceinline__ void gload_lds16(const void* g, void* l) {
    // async 16B global->LDS (DMA path); LDS dest = wave-uniform base + lane*16
    __builtin_amdgcn_global_load_lds((as1_cvp)g, (as3_vp)l, 16, 0, 0);
}

__device__ __forceinline__ unsigned short bf16_rne(float x) {
    unsigned u = __builtin_bit_cast(unsigned, x);
    unsigned r = (u + 0x7FFFu + ((u >> 16) & 1u)) >> 16;
    return (unsigned short)r;
}
__device__ __forceinline__ float bf16_to_f(unsigned short h) {
    unsigned u = ((unsigned)h) << 16;
    return __builtin_bit_cast(float, u);
}
// monotone float->u32 map: a<b  <=>  enc(a)<enc(b)
__device__ __forceinline__ unsigned enc_f32(float f) {
    unsigned u = __builtin_bit_cast(unsigned, f);
    return u ^ ((unsigned)((int)u >> 31) | 0x80000000u);
}

// ---------------- fused: zero accumulators + emb hi/lo split + e_sq ---------
// (unchanged from R5)
__global__ __launch_bounds__(256) void prep_zero_kernel(
        const float* __restrict__ emb,
        unsigned short* __restrict__ ehi, unsigned short* __restrict__ elo,
        float* __restrict__ e_sq, float* __restrict__ dw,
        int* __restrict__ counts, float* __restrict__ out) {
    int k = blockIdx.x;
    int t = threadIdx.x;
    dw[(size_t)k * DIM + t] = 0.0f;
    if (t == 64) counts[k] = 0;
    if (k == 0 && t == 128) out[O_LOSS] = 0.0f;
    if (t < 64) {
        int lane = t;
        const float4* ep = (const float4*)(emb + (size_t)k * DIM);
        float4 e = ep[lane];
        float x[4] = {e.x, e.y, e.z, e.w};
        unsigned h[4], l[4];
        float s = 0.0f;
        #pragma unroll
        for (int j = 0; j < 4; ++j) {
            h[j] = bf16_rne(x[j]);
            l[j] = bf16_rne(x[j] - bf16_to_f((unsigned short)h[j]));
            s += x[j] * x[j];
        }
        uint2 ph = make_uint2(h[0] | (h[1] << 16), h[2] | (h[3] << 16));
        uint2 pl = make_uint2(l[0] | (l[1] << 16), l[2] | (l[3] << 16));
        int slot = lane >> 1;            // 16B slot (8 ushorts)
        int half2 = lane & 1;            // which 8B half of the slot
        int us = k * 256 + ((slot ^ (k & 7)) << 3) + (half2 << 2);
        *(uint2*)(ehi + us) = ph;
        *(uint2*)(elo + us) = pl;
        for (int off = 32; off; off >>= 1) s += __shfl_down(s, off, 64);
        if (lane == 0) e_sq[k] = s;
    }
}

// ---------------- MFMA distance + argmin (counted-vmcnt deep pipeline) ------
// Grid 512: block = (row-group bm = blockIdx>>1, 256 rows) x (half = blockIdx&1,
// 512 codes).  8 waves x 32 rows.  Quad-buffered 16-code chunks staged 3 ahead
// via global_load_lds; raw s_barrier + COUNTED s_waitcnt vmcnt(6) -- DMA never
// drains to 0 in the main loop (T3+T4).  setprio(1) around MFMA cluster (T5).
// LDS = 4x(8+8) KB + 2 KB esq = 66 KB -> 2 blocks/CU = 16 waves/CU; VGPR
// pinned to 128 by __launch_bounds__(512,4) (natural need measured 128 in R5).
#define WAITVM(n) asm volatile("s_waitcnt vmcnt(" #n ")" ::: "memory")
__global__ __launch_bounds__(512, 4) void argmin_kernel(
        const float* __restrict__ z_e,
        const unsigned short* __restrict__ ehi,
        const unsigned short* __restrict__ elo,
        const float* __restrict__ e_sq,
        unsigned long long* __restrict__ part) {
    __shared__ __align__(16) unsigned short bhi_s[4][16 * 256]; // 4x8 KB
    __shared__ __align__(16) unsigned short blo_s[4][16 * 256]; // 4x8 KB
    __shared__ float esq_s[512];

    int tid = threadIdx.x;
    int w = tid >> 6;
    int lane = tid & 63;
    int m16 = lane & 15;
    int quad = lane >> 4;
    int hf = blockIdx.x & 1;
    int base_m = (blockIdx.x >> 1) * 256 + w * 32;
    const char* ehi_b = (const char*)ehi + hf * 262144;   // 512 rows * 512 B
    const char* elo_b = (const char*)elo + hf * 262144;

#define STAGE(c) { \
    int b_ = (c) & 3; \
    gload_lds16(ehi_b + (c) * 8192 + tid * 16, (char*)(bhi_s[b_]) + tid * 16); \
    gload_lds16(elo_b + (c) * 8192 + tid * 16, (char*)(blo_s[b_]) + tid * 16); }

    // stage chunks 0..3 (8 loads/wave in flight), overlap with A-conversion
    STAGE(0) STAGE(1) STAGE(2) STAGE(3)

    if (tid < 512) esq_s[tid] = e_sq[(hf << 9) + tid];

    // load + split A fragments: A[m=lane&15][k=quad*8+j]
    bf16x8 ahi[2][8], alo[2][8];
    #pragma unroll
    for (int f = 0; f < 2; ++f) {
        const float* zr = z_e + (size_t)(base_m + f * 16 + m16) * DIM;
        #pragma unroll
        for (int ks = 0; ks < 8; ++ks) {
            const float4* p = (const float4*)(zr + ks * 32 + quad * 8);
            float4 x0 = p[0], x1 = p[1];
            float xs[8] = {x0.x, x0.y, x0.z, x0.w, x1.x, x1.y, x1.z, x1.w};
            #pragma unroll
            for (int j = 0; j < 8; ++j) {
                unsigned short h = bf16_rne(xs[j]);
                unsigned short l = bf16_rne(xs[j] - bf16_to_f(h));
                ahi[f][ks][j] = (short)h;
                alo[f][ks][j] = (short)l;
            }
        }
    }

    float best0[4] = {1e30f, 1e30f, 1e30f, 1e30f};
    float best1[4] = {1e30f, 1e30f, 1e30f, 1e30f};
    int bk0[4] = {0, 0, 0, 0};
    int bk1[4] = {0, 0, 0, 0};

    const int rsw = (m16 & 7) << 3;   // read-side XOR (in ushort units)

#define COMPUTE(c) { \
    int b_ = (c) & 3; \
    f32x4 acc0 = {0.f, 0.f, 0.f, 0.f}; \
    f32x4 acc1 = {0.f, 0.f, 0.f, 0.f}; \
    const unsigned short* bh_row = bhi_s[b_] + m16 * 256; \
    const unsigned short* bl_row = blo_s[b_] + m16 * 256; \
    __builtin_amdgcn_s_setprio(1); \
    _Pragma("unroll") for (int ks_ = 0; ks_ < 8; ++ks_) { \
        int us_off = (((ks_ * 4 + quad) << 3) ^ rsw); \
        bf16x8 bh = *(const bf16x8*)(bh_row + us_off); \
        bf16x8 bl = *(const bf16x8*)(bl_row + us_off); \
        acc0 = __builtin_amdgcn_mfma_f32_16x16x32_bf16(ahi[0][ks_], bh, acc0, 0, 0, 0); \
        acc1 = __builtin_amdgcn_mfma_f32_16x16x32_bf16(ahi[1][ks_], bh, acc1, 0, 0, 0); \
        acc0 = __builtin_amdgcn_mfma_f32_16x16x32_bf16(ahi[0][ks_], bl, acc0, 0, 0, 0); \
        acc1 = __builtin_amdgcn_mfma_f32_16x16x32_bf16(ahi[1][ks_], bl, acc1, 0, 0, 0); \
        acc0 = __builtin_amdgcn_mfma_f32_16x16x32_bf16(alo[0][ks_], bh, acc0, 0, 0, 0); \
        acc1 = __builtin_amdgcn_mfma_f32_16x16x32_bf16(alo[1][ks_], bh, acc1, 0, 0, 0); } \
    __builtin_amdgcn_s_setprio(0); \
    int lcol = (c) * 16 + m16; \
    int col = (hf << 9) + lcol; \
    float es = esq_s[lcol]; \
    _Pragma("unroll") for (int r_ = 0; r_ < 4; ++r_) { \
        float d0 = es - 2.0f * acc0[r_]; \
        float d1 = es - 2.0f * acc1[r_]; \
        if (d0 < best0[r_]) { best0[r_] = d0; bk0[r_] = col; } \
        if (d1 < best1[r_]) { best1[r_] = d1; bk1[r_] = col; } } }

    // chunk0 ready (8 out -> wait to 6 = stage0 landed); esq/A deps drained
    asm volatile("s_waitcnt vmcnt(6) lgkmcnt(0)" ::: "memory");
    __builtin_amdgcn_s_barrier();

    // steady state: 3 chunks of DMA always in flight, vmcnt never hits 0
    for (int c = 0; c < 28; ++c) {
        COMPUTE(c)
        __builtin_amdgcn_s_barrier();   // all waves done reading buf[c&3]
        STAGE(c + 4)                    // refill just-freed buffer
        WAITVM(6);                      // oldest stage (c+1) landed
        __builtin_amdgcn_s_barrier();   // everyone's share of c+1 landed
    }
    // tail: drain 28..31 with counted waits
    COMPUTE(28)
    __builtin_amdgcn_s_barrier();
    WAITVM(4);
    __builtin_amdgcn_s_barrier();
    COMPUTE(29)
    __builtin_amdgcn_s_barrier();
    WAITVM(2);
    __builtin_amdgcn_s_barrier();
    COMPUTE(30)
    __builtin_amdgcn_s_barrier();
    WAITVM(0);
    __builtin_amdgcn_s_barrier();
    COMPUTE(31)

    #pragma unroll
    for (int off = 1; off < 16; off <<= 1) {
        #pragma unroll
        for (int r = 0; r < 4; ++r) {
            float ov0 = __shfl_xor(best0[r], off, 64);
            int   ok0 = __shfl_xor(bk0[r], off, 64);
            if (ov0 < best0[r] || (ov0 == best0[r] && ok0 < bk0[r])) { best0[r] = ov0; bk0[r] = ok0; }
            float ov1 = __shfl_xor(best1[r], off, 64);
            int   ok1 = __shfl_xor(bk1[r], off, 64);
            if (ov1 < best1[r] || (ov1 == best1[r] && ok1 < bk1[r])) { best1[r] = ov1; bk1[r] = ok1; }
        }
    }
    if (m16 == 0) {
        #pragma unroll
        for (int r = 0; r < 4; ++r) {
            int row0 = base_m + quad * 4 + r;
            int row1 = base_m + 16 + quad * 4 + r;
            unsigned long long k0 =
                ((unsigned long long)enc_f32(best0[r]) << 32) | (unsigned)bk0[r];
            unsigned long long k1 =
                ((unsigned long long)enc_f32(best1[r]) << 32) | (unsigned)bk1[r];
            part[row0 * 2 + hf] = k0;
            part[row1 * 2 + hf] = k1;
        }
    }
#undef STAGE
#undef COMPUTE
}

// ---------------- merge halves + idx outputs + histogram --------------------
__global__ __launch_bounds__(256) void combine_kernel(
        const unsigned long long* __restrict__ part,
        int* __restrict__ idx_out, float* __restrict__ idx_f_out,
        int* __restrict__ counts) {
    __shared__ int h[KC];
    int t = threadIdx.x;
    #pragma unroll
    for (int i = t; i < KC; i += 256) h[i] = 0;
    __syncthreads();
    int base = blockIdx.x * 512;
    #pragma unroll
    for (int j = 0; j < 2; ++j) {
        int row = base + j * 256 + t;
        unsigned long long k0 = part[row * 2];
        unsigned long long k1 = part[row * 2 + 1];
        unsigned long long m = k0 < k1 ? k0 : k1;
        int k = (int)(m & 0xFFFFFFFFu);
        idx_out[row] = k;
        idx_f_out[row] = (float)k;
        atomicAdd(&h[k], 1);
    }
    __syncthreads();
    #pragma unroll
    for (int i = t; i < KC; i += 256) if (h[i]) atomicAdd(&counts[i], h[i]);
}

// ---------------- prefix scan + cluster stats (ncs, n, perplexity) ----------
__global__ __launch_bounds__(1024) void prefix_stats_kernel(
        const int* __restrict__ counts, int* __restrict__ cursor,
        const float* __restrict__ ema_cs, float* __restrict__ out,
        float* __restrict__ n_ws) {
    __shared__ int wsum[16];
    __shared__ float s1[1024];
    __shared__ float s2[1024];
    int t = threadIdx.x;
    int lane = t & 63;
    int wv = t >> 6;
    int c = counts[t];
    int x = c;
    #pragma unroll
    for (int off = 1; off < 64; off <<= 1) {
        int v = __shfl_up(x, off, 64);
        if (lane >= off) x += v;
    }
    if (lane == 63) wsum[wv] = x;
    // cluster stats while the scan syncs
    float cf = (float)c;
    float ncs = DECAY * ema_cs[t] + (1.0f - DECAY) * cf;
    out[O_NCS + t] = ncs;
    float p = cf / (float)BATCH;
    s1[t] = ncs;
    s2[t] = p * logf(p + 1e-10f);
    __syncthreads();
    if (wv == 0) {
        int v = (lane < 16) ? wsum[lane] : 0;
        #pragma unroll
        for (int off = 1; off < 16; off <<= 1) {
            int u = __shfl_up(v, off, 64);
            if (lane >= off) v += u;
        }
        if (lane < 16) wsum[lane] = v;
    }
    __syncthreads();
    int woff = (wv == 0) ? 0 : wsum[wv - 1];
    cursor[t] = woff + x - c;   // exclusive
    for (int s = 512; s; s >>= 1) {
        if (t < s) { s1[t] += s1[t + s]; s2[t] += s2[t + s]; }
        __syncthreads();
    }
    if (t == 0) {
        n_ws[0] = s1[0];
        out[O_PERP] = expf(-s2[0]);
    }
}

// ---------------- bucket rows by cluster ------------------------------------
__global__ __launch_bounds__(256) void scatter_rows_kernel(
        const int* __restrict__ idx, int* __restrict__ cursor,
        int* __restrict__ sorted_rows) {
    int i = blockIdx.x * 256 + threadIdx.x;
    int k = idx[i];
    int pos = atomicAdd(&cursor[k], 1);
    sorted_rows[pos] = i;
}

// ---------------- fused: z_q gather + loss + dw ------------------------------
#define SEG 64
__global__ __launch_bounds__(256) void dw_zq_kernel(
        const float* __restrict__ z_e, const float* __restrict__ emb,
        const int* __restrict__ idx, const int* __restrict__ sorted_rows,
        float* __restrict__ zq_out, float* __restrict__ dw,
        float* __restrict__ out) {
    __shared__ int rows_s[SEG];
    __shared__ int keys_s[SEG];
    int t = threadIdx.x;
    int w = t >> 6;
    int lane = t & 63;
    int base = blockIdx.x * SEG;
    if (t < SEG) {
        int r = sorted_rows[base + t];
        rows_s[t] = r;
        keys_s[t] = idx[r];
    }
    __syncthreads();

    int c4 = lane * 4;
    float4 acc = make_float4(0.f, 0.f, 0.f, 0.f);
    float lsum = 0.0f;
    int kprev = keys_s[w * 16];
    #pragma unroll
    for (int g = 0; g < 2; ++g) {
        int rowb[8], kb[8];
        float4 zb[8], qb[8];
        #pragma unroll
        for (int u = 0; u < 8; ++u) {
            int i = w * 16 + g * 8 + u;
            rowb[u] = rows_s[i];
            kb[u] = keys_s[i];
        }
        #pragma unroll
        for (int u = 0; u < 8; ++u) {
            zb[u] = *(const float4*)(z_e + (size_t)rowb[u] * DIM + c4);
            qb[u] = *(const float4*)(emb + (size_t)kb[u] * DIM + c4);
        }
        #pragma unroll
        for (int u = 0; u < 8; ++u) {
            float4 z = zb[u], q = qb[u];
            float4 d = make_float4(q.x - z.x, q.y - z.y, q.z - z.z, q.w - z.w);
            float4 o = make_float4(z.x + d.x, z.y + d.y, z.z + d.z, z.w + d.w);
            *(float4*)(zq_out + (size_t)rowb[u] * DIM + c4) = o;
            lsum += d.x * d.x + d.y * d.y + d.z * d.z + d.w * d.w;
            if (kb[u] != kprev) {
                float* dst = dw + (size_t)kprev * DIM + c4;
                atomicAdd(dst + 0, acc.x);
                atomicAdd(dst + 1, acc.y);
                atomicAdd(dst + 2, acc.z);
                atomicAdd(dst + 3, acc.w);
                acc = make_float4(0.f, 0.f, 0.f, 0.f);
                kprev = kb[u];
            }
            acc.x += z.x; acc.y += z.y; acc.z += z.z; acc.w += z.w;
        }
    }
    {
        float* dst = dw + (size_t)kprev * DIM + c4;
        atomicAdd(dst + 0, acc.x);
        atomicAdd(dst + 1, acc.y);
        atomicAdd(dst + 2, acc.z);
        atomicAdd(dst + 3, acc.w);
    }

    __shared__ float red[256];
    red[t] = lsum;
    __syncthreads();
    for (int s = 128; s; s >>= 1) {
        if (t < s) red[t] += red[t + s];
        __syncthreads();
    }
    if (t == 0)
        atomicAdd(out + O_LOSS, red[0] * (COMMIT / ((float)BATCH * (float)DIM)));
}

// ---------------- new_ema_w and new_embedding -------------------------------
__global__ __launch_bounds__(256) void finalize_emb(
        const float* __restrict__ ema_w, const float* __restrict__ dw,
        const float* __restrict__ ncs_arr, const float* __restrict__ n_ws,
        float* __restrict__ out_emb, float* __restrict__ out_emaw) {
    int k = blockIdx.x;
    int d = threadIdx.x;
    size_t i = (size_t)k * DIM + d;
    float w = DECAY * ema_w[i] + (1.0f - DECAY) * dw[i];
    out_emaw[i] = w;
    float n = n_ws[0];
    float ncs = ncs_arr[k];
    float smoothed = (ncs + EPSV) / (n + (float)KC * EPSV) * n;
    out_emb[i] = w / smoothed;
}

extern "C" void kernel_launch(void* const* d_in, const int* in_sizes, int n_in,
                              void* d_out, int out_size, void* d_ws, size_t ws_size,
                              hipStream_t stream) {
    const float* z_e    = (const float*)d_in[0];
    const float* emb    = (const float*)d_in[1];
    const float* ema_cs = (const float*)d_in[2];
    const float* ema_w  = (const float*)d_in[3];
    float* out = (float*)d_out;
    float* ws = (float*)d_ws;

    // workspace layout (16B-aligned chunks first)
    float* dw            = ws;                                   // 262144 f
    unsigned short* ehi  = (unsigned short*)(dw + KC * DIM);     // 262144 us
    unsigned short* elo  = ehi + KC * DIM;                       // 262144 us
    unsigned long long* part = (unsigned long long*)(elo + KC * DIM); // 131072 u64
    float* e_sq          = (float*)(part + 2 * BATCH);           // 1024 f
    int* idx             = (int*)(e_sq + KC);                    // 65536 i
    int* counts          = idx + BATCH;                          // 1024 i
    int* cursor          = counts + KC;                          // 1024 i
    int* sorted_rows     = cursor + KC;                          // 65536 i
    float* n_ws          = (float*)(sorted_rows + BATCH);        // 1 f

    prep_zero_kernel<<<dim3(KC), dim3(256), 0, stream>>>(
        emb, ehi, elo, e_sq, dw, counts, out);
    argmin_kernel<<<dim3(BATCH / 256 * 2), dim3(512), 0, stream>>>(
        z_e, ehi, elo, e_sq, part);
    combine_kernel<<<dim3(BATCH / 512), dim3(256), 0, stream>>>(
        part, idx, out + O_IDX, counts);
    prefix_stats_kernel<<<dim3(1), dim3(1024), 0, stream>>>(
        counts, cursor, ema_cs, out, n_ws);
    scatter_rows_kernel<<<dim3(BATCH / 256), dim3(256), 0, stream>>>(
        idx, cursor, sorted_rows);
    dw_zq_kernel<<<dim3(BATCH / SEG), dim3(256), 0, stream>>>(
        z_e, emb, idx, sorted_rows, out + O_ZQ, dw, out);
    finalize_emb<<<dim3(KC), dim3(256), 0, stream>>>(
        ema_w, dw, out + O_NCS, n_ws, out + O_EMB, out + O_NEW);
}

// Round 7
// 336.394 us; speedup vs baseline: 1.8326x; 1.8326x over previous
//
#include <hip/hip_runtime.h>
#include <hip/hip_bf16.h>
#include <math.h>

#define BATCH 65536
#define DIM 256
#define KC 1024
#define COMMIT 0.25f
#define DECAY 0.99f
#define EPSV 1e-5f

// Output layout (floats, concatenated in reference return order)
#define O_ZQ   0                       // 65536*256
#define O_LOSS 16777216                // 1
#define O_PERP 16777217                // 1
#define O_IDX  16777218                // 65536 (indices written as float values)
#define O_EMB  16842754                // 1024*256 new_embedding
#define O_NCS  17104898                // 1024 new_ema_cluster_size
#define O_NEW  17105922                // 1024*256 new_ema_w

typedef __attribute__((ext_vector_type(8))) short bf16x8;
typedef __attribute__((ext_vector_type(4))) float f32x4;

typedef __attribute__((address_space(1))) const void* as1_cvp;
typedef __attribute__((address_space(3))) void* as3_vp;

__device__ __forceinline__ void gload_lds16(const void* g, void* l) {
    // async 16B global->LDS (DMA path); LDS dest = wave-uniform base + lane*16
    __builtin_amdgcn_global_load_lds((as1_cvp)g, (as3_vp)l, 16, 0, 0);
}

__device__ __forceinline__ unsigned short bf16_rne(float x) {
    unsigned u = __builtin_bit_cast(unsigned, x);
    unsigned r = (u + 0x7FFFu + ((u >> 16) & 1u)) >> 16;
    return (unsigned short)r;
}
__device__ __forceinline__ float bf16_to_f(unsigned short h) {
    unsigned u = ((unsigned)h) << 16;
    return __builtin_bit_cast(float, u);
}
// monotone float->u32 map: a<b  <=>  enc(a)<enc(b)
__device__ __forceinline__ unsigned enc_f32(float f) {
    unsigned u = __builtin_bit_cast(unsigned, f);
    return u ^ ((unsigned)((int)u >> 31) | 0x80000000u);
}

// ---------------- fused: zero accumulators + emb hi/lo split + e_sq ---------
// (unchanged from R5)
__global__ __launch_bounds__(256) void prep_zero_kernel(
        const float* __restrict__ emb,
        unsigned short* __restrict__ ehi, unsigned short* __restrict__ elo,
        float* __restrict__ e_sq, float* __restrict__ dw,
        int* __restrict__ counts, float* __restrict__ out) {
    int k = blockIdx.x;
    int t = threadIdx.x;
    dw[(size_t)k * DIM + t] = 0.0f;
    if (t == 64) counts[k] = 0;
    if (k == 0 && t == 128) out[O_LOSS] = 0.0f;
    if (t < 64) {
        int lane = t;
        const float4* ep = (const float4*)(emb + (size_t)k * DIM);
        float4 e = ep[lane];
        float x[4] = {e.x, e.y, e.z, e.w};
        unsigned h[4], l[4];
        float s = 0.0f;
        #pragma unroll
        for (int j = 0; j < 4; ++j) {
            h[j] = bf16_rne(x[j]);
            l[j] = bf16_rne(x[j] - bf16_to_f((unsigned short)h[j]));
            s += x[j] * x[j];
        }
        uint2 ph = make_uint2(h[0] | (h[1] << 16), h[2] | (h[3] << 16));
        uint2 pl = make_uint2(l[0] | (l[1] << 16), l[2] | (l[3] << 16));
        int slot = lane >> 1;            // 16B slot (8 ushorts)
        int half2 = lane & 1;            // which 8B half of the slot
        int us = k * 256 + ((slot ^ (k & 7)) << 3) + (half2 << 2);
        *(uint2*)(ehi + us) = ph;
        *(uint2*)(elo + us) = pl;
        for (int off = 32; off; off >>= 1) s += __shfl_down(s, off, 64);
        if (lane == 0) e_sq[k] = s;
    }
}

// ---------------- MFMA distance + argmin (counted-vmcnt, 3-buffer) ----------
// R5 geometry (grid 1024 = 512 row-groups x 2 halves, 256 thr, 4 waves, 128
// rows/block, 512 codes/block) -- proven 128-VGPR, no cap arg (R3/R6 lesson:
// min-waves arg w caps VGPR at 256/w; w>=4 forces 64 and spills).
// New K-loop: 3 LDS buffers, staged 2 ahead, ONE s_barrier per chunk, and
// counted s_waitcnt vmcnt(4) -- the newest stage stays in flight across the
// barrier (T4); vmcnt reaches 0 only in the 2-chunk tail.  setprio on MFMA.
// LDS = 3x(8+8) KB + 2 KB esq = 50 KB -> 3 blocks/CU = 12 waves/CU.
#define WAITVM(n) asm volatile("s_waitcnt vmcnt(" #n ")" ::: "memory")
__global__ __launch_bounds__(256) void argmin_kernel(
        const float* __restrict__ z_e,
        const unsigned short* __restrict__ ehi,
        const unsigned short* __restrict__ elo,
        const float* __restrict__ e_sq,
        unsigned long long* __restrict__ part) {
    __shared__ __align__(16) unsigned short bhi_s[3][16 * 256]; // 3x8 KB
    __shared__ __align__(16) unsigned short blo_s[3][16 * 256]; // 3x8 KB
    __shared__ float esq_s[512];

    int tid = threadIdx.x;
    int w = tid >> 6;
    int lane = tid & 63;
    int m16 = lane & 15;
    int quad = lane >> 4;
    int hf = blockIdx.x & 1;
    int base_m = (blockIdx.x >> 1) * 128 + w * 32;
    const char* ehi_b = (const char*)ehi + hf * 262144;   // 512 rows * 512 B
    const char* elo_b = (const char*)elo + hf * 262144;

// stage chunk c (16 KB: 8 hi + 8 lo) into buffer b; 4 loads/thread
#define STAGE(c, b) { \
    const char* gh_ = ehi_b + (c) * 8192 + tid * 16; \
    const char* gl_ = elo_b + (c) * 8192 + tid * 16; \
    char* lh_ = (char*)(bhi_s[b]) + tid * 16; \
    char* ll_ = (char*)(blo_s[b]) + tid * 16; \
    gload_lds16(gh_, lh_);          gload_lds16(gl_, ll_); \
    gload_lds16(gh_ + 4096, lh_ + 4096); gload_lds16(gl_ + 4096, ll_ + 4096); }

    // prologue: stage chunks 0,1 (8 loads in flight); A-conversion overlaps
    STAGE(0, 0)
    STAGE(1, 1)

    esq_s[tid] = e_sq[(hf << 9) + tid];
    esq_s[tid + 256] = e_sq[(hf << 9) + tid + 256];

    // load + split A fragments: A[m=lane&15][k=quad*8+j]
    bf16x8 ahi[2][8], alo[2][8];
    #pragma unroll
    for (int f = 0; f < 2; ++f) {
        const float* zr = z_e + (size_t)(base_m + f * 16 + m16) * DIM;
        #pragma unroll
        for (int ks = 0; ks < 8; ++ks) {
            const float4* p = (const float4*)(zr + ks * 32 + quad * 8);
            float4 x0 = p[0], x1 = p[1];
            float xs[8] = {x0.x, x0.y, x0.z, x0.w, x1.x, x1.y, x1.z, x1.w};
            #pragma unroll
            for (int j = 0; j < 8; ++j) {
                unsigned short h = bf16_rne(xs[j]);
                unsigned short l = bf16_rne(xs[j] - bf16_to_f(h));
                ahi[f][ks][j] = (short)h;
                alo[f][ks][j] = (short)l;
            }
        }
    }

    float best0[4] = {1e30f, 1e30f, 1e30f, 1e30f};
    float best1[4] = {1e30f, 1e30f, 1e30f, 1e30f};
    int bk0[4] = {0, 0, 0, 0};
    int bk1[4] = {0, 0, 0, 0};

    const int rsw = (m16 & 7) << 3;   // read-side XOR (in ushort units)

#define COMPUTE(c, b) { \
    f32x4 acc0 = {0.f, 0.f, 0.f, 0.f}; \
    f32x4 acc1 = {0.f, 0.f, 0.f, 0.f}; \
    const unsigned short* bh_row = bhi_s[b] + m16 * 256; \
    const unsigned short* bl_row = blo_s[b] + m16 * 256; \
    __builtin_amdgcn_s_setprio(1); \
    _Pragma("unroll") for (int ks_ = 0; ks_ < 8; ++ks_) { \
        int us_off = (((ks_ * 4 + quad) << 3) ^ rsw); \
        bf16x8 bh = *(const bf16x8*)(bh_row + us_off); \
        bf16x8 bl = *(const bf16x8*)(bl_row + us_off); \
        acc0 = __builtin_amdgcn_mfma_f32_16x16x32_bf16(ahi[0][ks_], bh, acc0, 0, 0, 0); \
        acc1 = __builtin_amdgcn_mfma_f32_16x16x32_bf16(ahi[1][ks_], bh, acc1, 0, 0, 0); \
        acc0 = __builtin_amdgcn_mfma_f32_16x16x32_bf16(ahi[0][ks_], bl, acc0, 0, 0, 0); \
        acc1 = __builtin_amdgcn_mfma_f32_16x16x32_bf16(ahi[1][ks_], bl, acc1, 0, 0, 0); \
        acc0 = __builtin_amdgcn_mfma_f32_16x16x32_bf16(alo[0][ks_], bh, acc0, 0, 0, 0); \
        acc1 = __builtin_amdgcn_mfma_f32_16x16x32_bf16(alo[1][ks_], bh, acc1, 0, 0, 0); } \
    __builtin_amdgcn_s_setprio(0); \
    int lcol = (c) * 16 + m16; \
    int col = (hf << 9) + lcol; \
    float es = esq_s[lcol]; \
    _Pragma("unroll") for (int r_ = 0; r_ < 4; ++r_) { \
        float d0 = es - 2.0f * acc0[r_]; \
        float d1 = es - 2.0f * acc1[r_]; \
        if (d0 < best0[r_]) { best0[r_] = d0; bk0[r_] = col; } \
        if (d1 < best1[r_]) { best1[r_] = d1; bk1[r_] = col; } } }

    // chunk0 landed (8 out -> 4); esq ds_writes drained; then sync
    asm volatile("s_waitcnt vmcnt(4) lgkmcnt(0)" ::: "memory");
    __builtin_amdgcn_s_barrier();

    // steady state: stage 2 ahead; newest stage never drained (vmcnt(4))
    for (int c = 0; c < 30; c += 3) {
        STAGE(c + 2, 2) COMPUTE(c, 0)
        WAITVM(4);
        __builtin_amdgcn_s_barrier();
        STAGE(c + 3, 0) COMPUTE(c + 1, 1)
        WAITVM(4);
        __builtin_amdgcn_s_barrier();
        STAGE(c + 4, 1) COMPUTE(c + 2, 2)
        WAITVM(4);
        __builtin_amdgcn_s_barrier();
    }
    // tail: chunks 30, 31 (staged in the last group); drain counted
    COMPUTE(30, 0)
    WAITVM(0);
    __builtin_amdgcn_s_barrier();
    COMPUTE(31, 1)

    #pragma unroll
    for (int off = 1; off < 16; off <<= 1) {
        #pragma unroll
        for (int r = 0; r < 4; ++r) {
            float ov0 = __shfl_xor(best0[r], off, 64);
            int   ok0 = __shfl_xor(bk0[r], off, 64);
            if (ov0 < best0[r] || (ov0 == best0[r] && ok0 < bk0[r])) { best0[r] = ov0; bk0[r] = ok0; }
            float ov1 = __shfl_xor(best1[r], off, 64);
            int   ok1 = __shfl_xor(bk1[r], off, 64);
            if (ov1 < best1[r] || (ov1 == best1[r] && ok1 < bk1[r])) { best1[r] = ov1; bk1[r] = ok1; }
        }
    }
    if (m16 == 0) {
        #pragma unroll
        for (int r = 0; r < 4; ++r) {
            int row0 = base_m + quad * 4 + r;
            int row1 = base_m + 16 + quad * 4 + r;
            unsigned long long k0 =
                ((unsigned long long)enc_f32(best0[r]) << 32) | (unsigned)bk0[r];
            unsigned long long k1 =
                ((unsigned long long)enc_f32(best1[r]) << 32) | (unsigned)bk1[r];
            part[row0 * 2 + hf] = k0;
            part[row1 * 2 + hf] = k1;
        }
    }
#undef STAGE
#undef COMPUTE
}

// ---------------- merge halves + idx outputs + histogram --------------------
__global__ __launch_bounds__(256) void combine_kernel(
        const unsigned long long* __restrict__ part,
        int* __restrict__ idx_out, float* __restrict__ idx_f_out,
        int* __restrict__ counts) {
    __shared__ int h[KC];
    int t = threadIdx.x;
    #pragma unroll
    for (int i = t; i < KC; i += 256) h[i] = 0;
    __syncthreads();
    int base = blockIdx.x * 512;
    #pragma unroll
    for (int j = 0; j < 2; ++j) {
        int row = base + j * 256 + t;
        unsigned long long k0 = part[row * 2];
        unsigned long long k1 = part[row * 2 + 1];
        unsigned long long m = k0 < k1 ? k0 : k1;
        int k = (int)(m & 0xFFFFFFFFu);
        idx_out[row] = k;
        idx_f_out[row] = (float)k;
        atomicAdd(&h[k], 1);
    }
    __syncthreads();
    #pragma unroll
    for (int i = t; i < KC; i += 256) if (h[i]) atomicAdd(&counts[i], h[i]);
}

// ---------------- prefix scan + cluster stats (ncs, n, perplexity) ----------
__global__ __launch_bounds__(1024) void prefix_stats_kernel(
        const int* __restrict__ counts, int* __restrict__ cursor,
        const float* __restrict__ ema_cs, float* __restrict__ out,
        float* __restrict__ n_ws) {
    __shared__ int wsum[16];
    __shared__ float s1[1024];
    __shared__ float s2[1024];
    int t = threadIdx.x;
    int lane = t & 63;
    int wv = t >> 6;
    int c = counts[t];
    int x = c;
    #pragma unroll
    for (int off = 1; off < 64; off <<= 1) {
        int v = __shfl_up(x, off, 64);
        if (lane >= off) x += v;
    }
    if (lane == 63) wsum[wv] = x;
    // cluster stats while the scan syncs
    float cf = (float)c;
    float ncs = DECAY * ema_cs[t] + (1.0f - DECAY) * cf;
    out[O_NCS + t] = ncs;
    float p = cf / (float)BATCH;
    s1[t] = ncs;
    s2[t] = p * logf(p + 1e-10f);
    __syncthreads();
    if (wv == 0) {
        int v = (lane < 16) ? wsum[lane] : 0;
        #pragma unroll
        for (int off = 1; off < 16; off <<= 1) {
            int u = __shfl_up(v, off, 64);
            if (lane >= off) v += u;
        }
        if (lane < 16) wsum[lane] = v;
    }
    __syncthreads();
    int woff = (wv == 0) ? 0 : wsum[wv - 1];
    cursor[t] = woff + x - c;   // exclusive
    for (int s = 512; s; s >>= 1) {
        if (t < s) { s1[t] += s1[t + s]; s2[t] += s2[t + s]; }
        __syncthreads();
    }
    if (t == 0) {
        n_ws[0] = s1[0];
        out[O_PERP] = expf(-s2[0]);
    }
}

// ---------------- bucket rows by cluster ------------------------------------
__global__ __launch_bounds__(256) void scatter_rows_kernel(
        const int* __restrict__ idx, int* __restrict__ cursor,
        int* __restrict__ sorted_rows) {
    int i = blockIdx.x * 256 + threadIdx.x;
    int k = idx[i];
    int pos = atomicAdd(&cursor[k], 1);
    sorted_rows[pos] = i;
}

// ---------------- fused: z_q gather + loss + dw ------------------------------
#define SEG 64
__global__ __launch_bounds__(256) void dw_zq_kernel(
        const float* __restrict__ z_e, const float* __restrict__ emb,
        const int* __restrict__ idx, const int* __restrict__ sorted_rows,
        float* __restrict__ zq_out, float* __restrict__ dw,
        float* __restrict__ out) {
    __shared__ int rows_s[SEG];
    __shared__ int keys_s[SEG];
    int t = threadIdx.x;
    int w = t >> 6;
    int lane = t & 63;
    int base = blockIdx.x * SEG;
    if (t < SEG) {
        int r = sorted_rows[base + t];
        rows_s[t] = r;
        keys_s[t] = idx[r];
    }
    __syncthreads();

    int c4 = lane * 4;
    float4 acc = make_float4(0.f, 0.f, 0.f, 0.f);
    float lsum = 0.0f;
    int kprev = keys_s[w * 16];
    #pragma unroll
    for (int g = 0; g < 2; ++g) {
        int rowb[8], kb[8];
        float4 zb[8], qb[8];
        #pragma unroll
        for (int u = 0; u < 8; ++u) {
            int i = w * 16 + g * 8 + u;
            rowb[u] = rows_s[i];
            kb[u] = keys_s[i];
        }
        #pragma unroll
        for (int u = 0; u < 8; ++u) {
            zb[u] = *(const float4*)(z_e + (size_t)rowb[u] * DIM + c4);
            qb[u] = *(const float4*)(emb + (size_t)kb[u] * DIM + c4);
        }
        #pragma unroll
        for (int u = 0; u < 8; ++u) {
            float4 z = zb[u], q = qb[u];
            float4 d = make_float4(q.x - z.x, q.y - z.y, q.z - z.z, q.w - z.w);
            float4 o = make_float4(z.x + d.x, z.y + d.y, z.z + d.z, z.w + d.w);
            *(float4*)(zq_out + (size_t)rowb[u] * DIM + c4) = o;
            lsum += d.x * d.x + d.y * d.y + d.z * d.z + d.w * d.w;
            if (kb[u] != kprev) {
                float* dst = dw + (size_t)kprev * DIM + c4;
                atomicAdd(dst + 0, acc.x);
                atomicAdd(dst + 1, acc.y);
                atomicAdd(dst + 2, acc.z);
                atomicAdd(dst + 3, acc.w);
                acc = make_float4(0.f, 0.f, 0.f, 0.f);
                kprev = kb[u];
            }
            acc.x += z.x; acc.y += z.y; acc.z += z.z; acc.w += z.w;
        }
    }
    {
        float* dst = dw + (size_t)kprev * DIM + c4;
        atomicAdd(dst + 0, acc.x);
        atomicAdd(dst + 1, acc.y);
        atomicAdd(dst + 2, acc.z);
        atomicAdd(dst + 3, acc.w);
    }

    __shared__ float red[256];
    red[t] = lsum;
    __syncthreads();
    for (int s = 128; s; s >>= 1) {
        if (t < s) red[t] += red[t + s];
        __syncthreads();
    }
    if (t == 0)
        atomicAdd(out + O_LOSS, red[0] * (COMMIT / ((float)BATCH * (float)DIM)));
}

// ---------------- new_ema_w and new_embedding -------------------------------
__global__ __launch_bounds__(256) void finalize_emb(
        const float* __restrict__ ema_w, const float* __restrict__ dw,
        const float* __restrict__ ncs_arr, const float* __restrict__ n_ws,
        float* __restrict__ out_emb, float* __restrict__ out_emaw) {
    int k = blockIdx.x;
    int d = threadIdx.x;
    size_t i = (size_t)k * DIM + d;
    float w = DECAY * ema_w[i] + (1.0f - DECAY) * dw[i];
    out_emaw[i] = w;
    float n = n_ws[0];
    float ncs = ncs_arr[k];
    float smoothed = (ncs + EPSV) / (n + (float)KC * EPSV) * n;
    out_emb[i] = w / smoothed;
}

extern "C" void kernel_launch(void* const* d_in, const int* in_sizes, int n_in,
                              void* d_out, int out_size, void* d_ws, size_t ws_size,
                              hipStream_t stream) {
    const float* z_e    = (const float*)d_in[0];
    const float* emb    = (const float*)d_in[1];
    const float* ema_cs = (const float*)d_in[2];
    const float* ema_w  = (const float*)d_in[3];
    float* out = (float*)d_out;
    float* ws = (float*)d_ws;

    // workspace layout (16B-aligned chunks first)
    float* dw            = ws;                                   // 262144 f
    unsigned short* ehi  = (unsigned short*)(dw + KC * DIM);     // 262144 us
    unsigned short* elo  = ehi + KC * DIM;                       // 262144 us
    unsigned long long* part = (unsigned long long*)(elo + KC * DIM); // 131072 u64
    float* e_sq          = (float*)(part + 2 * BATCH);           // 1024 f
    int* idx             = (int*)(e_sq + KC);                    // 65536 i
    int* counts          = idx + BATCH;                          // 1024 i
    int* cursor          = counts + KC;                          // 1024 i
    int* sorted_rows     = cursor + KC;                          // 65536 i
    float* n_ws          = (float*)(sorted_rows + BATCH);        // 1 f

    prep_zero_kernel<<<dim3(KC), dim3(256), 0, stream>>>(
        emb, ehi, elo, e_sq, dw, counts, out);
    argmin_kernel<<<dim3(BATCH / 128 * 2), dim3(256), 0, stream>>>(
        z_e, ehi, elo, e_sq, part);
    combine_kernel<<<dim3(BATCH / 512), dim3(256), 0, stream>>>(
        part, idx, out + O_IDX, counts);
    prefix_stats_kernel<<<dim3(1), dim3(1024), 0, stream>>>(
        counts, cursor, ema_cs, out, n_ws);
    scatter_rows_kernel<<<dim3(BATCH / 256), dim3(256), 0, stream>>>(
        idx, cursor, sorted_rows);
    dw_zq_kernel<<<dim3(BATCH / SEG), dim3(256), 0, stream>>>(
        z_e, emb, idx, sorted_rows, out + O_ZQ, dw, out);
    finalize_emb<<<dim3(KC), dim3(256), 0, stream>>>(
        ema_w, dw, out + O_NCS, n_ws, out + O_EMB, out + O_NEW);
}